// Round 11
// baseline (236.369 us; speedup 1.0000x reference)
//
#include <hip/hip_runtime.h>

#define N_ENTITIES 100000
#define N_USERS 50000
#define CHANNEL 64
#define N_RELATIONS 16
#define N_FACTORS 4
#define N_EDGES 1600000
#define N_INTER 1000000
#define TMASK ((1 << 17) - 1)

// buckets of 32 rows (scatter and gather granularity)
#define BSH 5
#define BSZ 32
#define NBE 3125      // 100000/32 exact
#define NBU 1563      // ceil(50000/32)
#define CAP_E 768     // per-bucket cap (mean 512, sigma ~23)
#define CAP_U 896     // per-bucket cap (mean 640, sigma ~25)
#define TILE_E 2048
#define TILE_U 2048
#define NTBE 782      // ceil(N_EDGES/TILE_E)
#define NTBU 489      // ceil(N_INTER/TILE_U)
#define NCONV 6250    // N_ENTITIES*CHANNEL/4 / 256
#define NHIST 256
#define NWORK 2048    // persistent gather blocks (256 CU x 8)

typedef unsigned short u16;

__device__ __forceinline__ float wave_reduce_sum(float p) {
    #pragma unroll
    for (int off = 32; off > 0; off >>= 1) p += __shfl_xor(p, off);
    return p;
}

// block-wide (1024 thr) inclusive scan via per-wave shfl scans; total in wsum[15]
__device__ __forceinline__ int block_scan_incl(int v, int* wsum) {
    int lane = threadIdx.x & 63, wid = threadIdx.x >> 6;
    int x = v;
    #pragma unroll
    for (int off = 1; off < 64; off <<= 1) {
        int y = __shfl_up(x, off);
        if (lane >= off) x += y;
    }
    __syncthreads();
    if (lane == 63) wsum[wid] = x;
    __syncthreads();
    if (wid == 0) {
        int s = (lane < 16) ? wsum[lane] : 0;
        #pragma unroll
        for (int off = 1; off < 16; off <<= 1) {
            int y = __shfl_up(s, off);
            if (lane >= off) s += y;
        }
        if (lane < 16) wsum[lane] = s;
    }
    __syncthreads();
    return x + (wid ? wsum[wid - 1] : 0);
}

__device__ __forceinline__ u16 f32_to_bf16_rne(float x) {
    unsigned u = __float_as_uint(x);
    return (u16)((u + 0x7FFFu + ((u >> 16) & 1u)) >> 16);
}

template <bool BF16>
__device__ __forceinline__ float ldrow(const float* __restrict__ e32,
                                       const u16* __restrict__ e16,
                                       int row, int lane) {
    if (BF16) return __uint_as_float(((unsigned)e16[(size_t)row * CHANNEL + lane]) << 16);
    return e32[(size_t)row * CHANNEL + lane];
}

// ---------------------------------------------------------------------------
// disen = softmax(disen_weight_att, axis=-1) @ weight   [4 x 64]
// ---------------------------------------------------------------------------
__device__ __forceinline__ void disen_body(const float* __restrict__ dwa,
                                           const float* __restrict__ weight,
                                           float* __restrict__ disen) {
    int f = threadIdx.x >> 6;
    int c = threadIdx.x & 63;
    float m = -INFINITY;
    #pragma unroll
    for (int r = 0; r < N_RELATIONS; ++r) m = fmaxf(m, dwa[f * N_RELATIONS + r]);
    float denom = 0.f, acc = 0.f;
    #pragma unroll
    for (int r = 0; r < N_RELATIONS; ++r) {
        float e = expf(dwa[f * N_RELATIONS + r] - m);
        denom += e;
        acc += e * weight[r * CHANNEL + c];
    }
    disen[f * CHANNEL + c] = acc / denom;
}

__global__ void disen_kernel(const float* __restrict__ dwa,
                             const float* __restrict__ weight,
                             float* __restrict__ disen) {
    disen_body(dwa, weight, disen);
}

// ---------------------------------------------------------------------------
// PREP: blocks [0,NCONV) bf16-convert; block NCONV disen; rest histogram.
// ---------------------------------------------------------------------------
__global__ __launch_bounds__(256) void prep_kernel(
    const float* __restrict__ src, u16* __restrict__ dst,
    const float* __restrict__ dwa, const float* __restrict__ weight,
    float* __restrict__ disen,
    const int* __restrict__ head, const int* __restrict__ irows,
    int* __restrict__ wp_e, int* __restrict__ wp_u) {
    __shared__ int lh[NBE + NBU];
    int bid = blockIdx.x;
    int tid = threadIdx.x;
    if (bid < NCONV) {
        int i = bid * 256 + tid;
        float4 v = ((const float4*)src)[i];
        ushort4 o;
        o.x = f32_to_bf16_rne(v.x);
        o.y = f32_to_bf16_rne(v.y);
        o.z = f32_to_bf16_rne(v.z);
        o.w = f32_to_bf16_rne(v.w);
        ((ushort4*)dst)[i] = o;
        return;
    }
    if (bid == NCONV) { disen_body(dwa, weight, disen); return; }
    for (int i = tid; i < NBE + NBU; i += 256) lh[i] = 0;
    __syncthreads();
    const int NTOT = N_EDGES + N_INTER;
    int hb = bid - NCONV - 1;
    for (int i = hb * 256 + tid; i < NTOT; i += NHIST * 256) {
        if (i < N_EDGES) atomicAdd(&lh[head[i] >> BSH], 1);
        else             atomicAdd(&lh[NBE + (irows[i - N_EDGES] >> BSH)], 1);
    }
    __syncthreads();
    for (int i = tid; i < NBE + NBU; i += 256) {
        int c = lh[i];
        if (c) {
            if (i < NBE) atomicAdd(&wp_e[i], c);
            else         atomicAdd(&wp_u[i - NBE], c);
        }
    }
}

// fallback hist without bf16 conversion
__global__ __launch_bounds__(1024) void hist_kernel(
    const int* __restrict__ head, const int* __restrict__ irows,
    int* __restrict__ wp_e, int* __restrict__ wp_u) {
    __shared__ int lh[NBE + NBU];
    int tid = threadIdx.x;
    for (int i = tid; i < NBE + NBU; i += 1024) lh[i] = 0;
    __syncthreads();
    const int NTOT = N_EDGES + N_INTER;
    for (int i = blockIdx.x * 1024 + tid; i < NTOT; i += gridDim.x * 1024) {
        if (i < N_EDGES) atomicAdd(&lh[head[i] >> BSH], 1);
        else             atomicAdd(&lh[NBE + (irows[i - N_EDGES] >> BSH)], 1);
    }
    __syncthreads();
    for (int i = tid; i < NBE + NBU; i += 1024) {
        int c = lh[i];
        if (c) {
            if (i < NBE) atomicAdd(&wp_e[i], c);
            else         atomicAdd(&wp_u[i - NBE], c);
        }
    }
}

// ---------------------------------------------------------------------------
// One-block chunked exclusive scans over wp_e (3125) and wp_u (1563).
// ---------------------------------------------------------------------------
__global__ __launch_bounds__(1024) void scan_kernel(
    int* __restrict__ wp_e, int* __restrict__ coff_e,
    int* __restrict__ wp_u, int* __restrict__ coff_u) {
    __shared__ int wsum[16];
    int tid = threadIdx.x;
    int run = 0;
    for (int c0 = 0; c0 < NBE; c0 += 1024) {
        int i = c0 + tid;
        int v = (i < NBE) ? wp_e[i] : 0;
        int incl = block_scan_incl(v, wsum) + run;
        run += wsum[15];
        if (i < NBE) { int ex = incl - v; coff_e[i] = ex; wp_e[i] = ex; }
    }
    if (tid == 0) coff_e[NBE] = N_EDGES;
    run = 0;
    for (int c0 = 0; c0 < NBU; c0 += 1024) {
        int i = c0 + tid;
        int v = (i < NBU) ? wp_u[i] : 0;
        int incl = block_scan_incl(v, wsum) + run;
        run += wsum[15];
        if (i < NBU) { int ex = incl - v; coff_u[i] = ex; wp_u[i] = ex; }
    }
    if (tid == 0) coff_u[NBU] = N_INTER;
}

// ---------------------------------------------------------------------------
// MERGED multisplit scatter at 32-row granularity.
// Blocks [0,NTBE): edge tiles (2048); rest: inter tiles (2048).
// Edge payload: (head&31)<<21 | (et-1)<<17 | tail.
// Inter payloads: (row&31)<<17 | col ; val.
// ---------------------------------------------------------------------------
__global__ __launch_bounds__(1024) void scatter_kernel(
    const int* __restrict__ head, const int* __restrict__ tail,
    const int* __restrict__ etype,
    const int* __restrict__ irows, const int* __restrict__ icols,
    const float* __restrict__ vals,
    int* __restrict__ wp_e, int* __restrict__ pay_e,
    int* __restrict__ wp_u, int* __restrict__ payA_u, float* __restrict__ payB_u) {
    __shared__ __align__(16) char smem[53888];
    __shared__ int wsum[16];
    int tid = threadIdx.x;
    int bid = blockIdx.x;

    if (bid < NTBE) {
        int* s_hist  = (int*)smem;            // NBE
        int* s_lofs  = s_hist + NBE;          // NBE
        int* s_gbase = s_lofs + NBE;          // NBE
        int* s_pay   = s_gbase + NBE;         // TILE_E
        int* s_dest  = s_pay + TILE_E;        // TILE_E
        int g0 = bid * TILE_E;
        int tilecnt = min(TILE_E, N_EDGES - g0);
        for (int i = tid; i < NBE; i += 1024) s_hist[i] = 0;
        int cb[2], pp[2], rk[2];
        __syncthreads();
        #pragma unroll
        for (int j = 0; j < 2; ++j) {
            int s = j * 1024 + tid;
            if (s < tilecnt) {
                int i = g0 + s;
                int h = head[i];
                cb[j] = h >> BSH;
                pp[j] = ((h & (BSZ - 1)) << 21) | ((etype[i] - 1) << 17) | tail[i];
            } else cb[j] = -1;
        }
        #pragma unroll
        for (int j = 0; j < 2; ++j)
            if (cb[j] >= 0) rk[j] = atomicAdd(&s_hist[cb[j]], 1);
        __syncthreads();
        int run = 0;
        for (int c0 = 0; c0 < NBE; c0 += 1024) {
            int i = c0 + tid;
            int c = (i < NBE) ? s_hist[i] : 0;
            int incl = block_scan_incl(c, wsum) + run;
            run += wsum[15];
            if (i < NBE) {
                int ex = incl - c;
                s_lofs[i] = ex;
                if (c > 0) s_gbase[i] = atomicAdd(&wp_e[i], c) - ex;
            }
        }
        __syncthreads();
        #pragma unroll
        for (int j = 0; j < 2; ++j) {
            if (cb[j] >= 0) {
                int slot = s_lofs[cb[j]] + rk[j];
                s_pay[slot]  = pp[j];
                s_dest[slot] = s_gbase[cb[j]] + slot;
            }
        }
        __syncthreads();
        #pragma unroll
        for (int j = 0; j < 2; ++j) {
            int s = j * 1024 + tid;
            if (s < tilecnt) pay_e[s_dest[s]] = s_pay[s];
        }
    } else {
        int*   s_hist  = (int*)smem;           // NBU
        int*   s_lofs  = s_hist + NBU;         // NBU
        int*   s_gbase = s_lofs + NBU;         // NBU
        int*   s_pay   = s_gbase + NBU;        // TILE_U
        float* s_val   = (float*)(s_pay + TILE_U);  // TILE_U
        int*   s_dest  = (int*)(s_val + TILE_U);    // TILE_U
        int g0 = (bid - NTBE) * TILE_U;
        int tilecnt = min(TILE_U, N_INTER - g0);
        for (int i = tid; i < NBU; i += 1024) s_hist[i] = 0;
        int cb[2], pp[2], rk[2];
        float vv[2];
        __syncthreads();
        #pragma unroll
        for (int j = 0; j < 2; ++j) {
            int s = j * 1024 + tid;
            if (s < tilecnt) {
                int i = g0 + s;
                int u = irows[i];
                cb[j] = u >> BSH;
                pp[j] = ((u & (BSZ - 1)) << 17) | icols[i];
                vv[j] = vals[i];
            } else cb[j] = -1;
        }
        #pragma unroll
        for (int j = 0; j < 2; ++j)
            if (cb[j] >= 0) rk[j] = atomicAdd(&s_hist[cb[j]], 1);
        __syncthreads();
        int run = 0;
        for (int c0 = 0; c0 < NBU; c0 += 1024) {
            int i = c0 + tid;
            int c = (i < NBU) ? s_hist[i] : 0;
            int incl = block_scan_incl(c, wsum) + run;
            run += wsum[15];
            if (i < NBU) {
                int ex = incl - c;
                s_lofs[i] = ex;
                if (c > 0) s_gbase[i] = atomicAdd(&wp_u[i], c) - ex;
            }
        }
        __syncthreads();
        #pragma unroll
        for (int j = 0; j < 2; ++j) {
            if (cb[j] >= 0) {
                int slot = s_lofs[cb[j]] + rk[j];
                s_pay[slot]  = pp[j];
                s_val[slot]  = vv[j];
                s_dest[slot] = s_gbase[cb[j]] + slot;
            }
        }
        __syncthreads();
        #pragma unroll
        for (int j = 0; j < 2; ++j) {
            int s = j * 1024 + tid;
            if (s < tilecnt) {
                payA_u[s_dest[s]] = s_pay[s];
                payB_u[s_dest[s]] = s_val[s];
            }
        }
    }
}

// ---------------------------------------------------------------------------
// PERSISTENT work-stealing gather: 2048 blocks x 256 thr; units = 32-row
// buckets (edges first, then users) pulled off a global counter.
// Weights/latent/disen staged once per block. In-LDS counting sort by local
// row, register-accumulate segments with unroll-8 MLP, nontemporal stores.
// ---------------------------------------------------------------------------
template <bool BF16>
__global__ __launch_bounds__(256, 8) void gather_kernel(
    const float* __restrict__ entity_emb,
    const u16* __restrict__ emb16,
    const float* __restrict__ weight,
    const float* __restrict__ user_emb,
    const float* __restrict__ latent_emb,
    const float* __restrict__ disen,
    const int* __restrict__ coff_e,
    const int* __restrict__ pay_e,
    const int* __restrict__ coff_u,
    const int* __restrict__ payA_u,
    const float* __restrict__ payB_u,
    int* __restrict__ unit_ctr,
    float* __restrict__ entity_agg,
    float* __restrict__ user_agg) {
    __shared__ float w65[N_RELATIONS * 65];    // 4160 B
    __shared__ float s_lat[N_FACTORS * CHANNEL];
    __shared__ float s_dis[N_FACTORS * CHANNEL];
    __shared__ float s_attv[BSZ * N_RELATIONS];
    __shared__ int   s_pay[CAP_U];             // max(CAP_E, CAP_U)
    __shared__ float s_val[CAP_U];
    __shared__ int   s_hist[BSZ], s_scan[BSZ];
    __shared__ int   s_unit;

    int tid = threadIdx.x;
    int wv = tid >> 6, lane = tid & 63;

    // stage constants once per block
    for (int i = tid; i < N_RELATIONS * CHANNEL; i += 256)
        w65[(i >> 6) * 65 + (i & 63)] = weight[i];
    s_lat[tid] = latent_emb[tid];
    s_dis[tid] = disen[tid];

    for (;;) {
        __syncthreads();   // protect LDS from previous unit; constants ready
        if (tid == 0) s_unit = atomicAdd(unit_ctr, 1);
        __syncthreads();
        int u = s_unit;
        if (u >= NBE + NBU) break;

        if (u < NBE) {
            // ---------------- edge unit (32 entities) ----------------
            if (tid < BSZ) s_hist[tid] = 0;
            int kbeg = coff_e[u];
            int n = min(coff_e[u + 1] - kbeg, CAP_E);
            __syncthreads();

            int myp[CAP_E / 256], myr[CAP_E / 256];
            #pragma unroll
            for (int j = 0; j < CAP_E / 256; ++j) {
                int s = j * 256 + tid;
                if (s < n) {
                    int p = pay_e[kbeg + s];
                    myp[j] = p;
                    myr[j] = atomicAdd(&s_hist[p >> 21], 1);
                }
            }
            __syncthreads();
            if (tid < BSZ) {   // 32-bin inclusive scan in wave 0
                int x = s_hist[tid];
                #pragma unroll
                for (int off = 1; off < BSZ; off <<= 1) {
                    int y = __shfl_up(x, off);
                    if (tid >= off) x += y;
                }
                s_scan[tid] = x;
            }
            __syncthreads();
            #pragma unroll
            for (int j = 0; j < CAP_E / 256; ++j) {
                int s = j * 256 + tid;
                if (s < n) {
                    int key = myp[j] >> 21;
                    s_pay[s_scan[key] - s_hist[key] + myr[j]] = myp[j];
                }
            }

            // att table: wave wv computes rows [wv*8, wv*8+8)
            int r = lane >> 2, q = lane & 3;
            #pragma unroll
            for (int t = 0; t < 8; ++t) {
                int le = wv * 8 + t;
                int ge = u * BSZ + le;     // exact: NBE*32 == N_ENTITIES
                float eh = ldrow<BF16>(entity_emb, emb16, ge, lane);
                float p = 0.f;
                #pragma unroll
                for (int j = 0; j < 16; ++j)
                    p += __shfl(eh, q * 16 + j) * w65[r * 65 + q * 16 + j];
                p += __shfl_xor(p, 1);
                p += __shfl_xor(p, 2);
                if (q == 0) s_attv[(le << 4) + r] = 1.f / (1.f + expf(-p));
            }
            __syncthreads();

            #define ELD(i, K) int p##i = s_pay[K]; \
                float v##i = ldrow<BF16>(entity_emb, emb16, p##i & TMASK, lane);
            #define EACC(i) { int et = (p##i >> 17) & 15; \
                acc += s_attv[(le << 4) + et] * v##i * w65[et * 65 + lane]; }
            for (int t = 0; t < 8; ++t) {
                int le = wv * 8 + t;
                int ge = u * BSZ + le;
                int cnt = s_hist[le];
                int ke = s_scan[le];
                int k = ke - cnt;
                float acc = 0.f;
                for (; k + 8 <= ke; k += 8) {
                    ELD(0, k)     ELD(1, k + 1) ELD(2, k + 2) ELD(3, k + 3)
                    ELD(4, k + 4) ELD(5, k + 5) ELD(6, k + 6) ELD(7, k + 7)
                    EACC(0) EACC(1) EACC(2) EACC(3)
                    EACC(4) EACC(5) EACC(6) EACC(7)
                }
                for (; k + 4 <= ke; k += 4) {
                    ELD(0, k) ELD(1, k + 1) ELD(2, k + 2) ELD(3, k + 3)
                    EACC(0) EACC(1) EACC(2) EACC(3)
                }
                for (; k < ke; ++k) {
                    ELD(0, k)
                    EACC(0)
                }
                __builtin_nontemporal_store(acc / fmaxf((float)cnt, 1.0f),
                                            &entity_agg[(size_t)ge * CHANNEL + lane]);
            }
            #undef ELD
            #undef EACC
        } else {
            // ---------------- user unit (32 users) ----------------
            int b = u - NBE;
            if (tid < BSZ) s_hist[tid] = 0;
            int kbeg = coff_u[b];
            int n = min(coff_u[b + 1] - kbeg, CAP_U);
            __syncthreads();

            int myp[CAP_U / 256 + 1], myr[CAP_U / 256 + 1];
            float myv[CAP_U / 256 + 1];
            #pragma unroll
            for (int j = 0; j < CAP_U / 256 + 1; ++j) {
                int s = j * 256 + tid;
                if (s < n) {
                    int p = payA_u[kbeg + s];
                    myp[j] = p;
                    myv[j] = payB_u[kbeg + s];
                    myr[j] = atomicAdd(&s_hist[p >> 17], 1);
                }
            }
            __syncthreads();
            if (tid < BSZ) {
                int x = s_hist[tid];
                #pragma unroll
                for (int off = 1; off < BSZ; off <<= 1) {
                    int y = __shfl_up(x, off);
                    if (tid >= off) x += y;
                }
                s_scan[tid] = x;
            }
            __syncthreads();
            #pragma unroll
            for (int j = 0; j < CAP_U / 256 + 1; ++j) {
                int s = j * 256 + tid;
                if (s < n) {
                    int key = myp[j] >> 17;
                    int slot = s_scan[key] - s_hist[key] + myr[j];
                    s_pay[slot] = myp[j] & TMASK;
                    s_val[slot] = myv[j];
                }
            }
            __syncthreads();

            #define ULD(i, K) int c##i = s_pay[K]; float x##i = s_val[K]; \
                float v##i = ldrow<BF16>(entity_emb, emb16, c##i, lane);
            for (int t = 0; t < 8; ++t) {
                int lu = wv * 8 + t;
                int gu = b * BSZ + lu;
                if (gu >= N_USERS) break;
                int cnt = s_hist[lu];
                int ke = s_scan[lu];
                int k = ke - cnt;
                float acc = 0.f;
                for (; k + 8 <= ke; k += 8) {
                    ULD(0, k)     ULD(1, k + 1) ULD(2, k + 2) ULD(3, k + 3)
                    ULD(4, k + 4) ULD(5, k + 5) ULD(6, k + 6) ULD(7, k + 7)
                    acc += x0 * v0 + x1 * v1 + x2 * v2 + x3 * v3;
                    acc += x4 * v4 + x5 * v5 + x6 * v6 + x7 * v7;
                }
                for (; k + 4 <= ke; k += 4) {
                    ULD(0, k) ULD(1, k + 1) ULD(2, k + 2) ULD(3, k + 3)
                    acc += x0 * v0 + x1 * v1 + x2 * v2 + x3 * v3;
                }
                for (; k < ke; ++k) {
                    ULD(0, k)
                    acc += x0 * v0;
                }

                float ue = user_emb[(size_t)gu * CHANNEL + lane];
                float s[N_FACTORS];
                #pragma unroll
                for (int f = 0; f < N_FACTORS; ++f)
                    s[f] = wave_reduce_sum(ue * s_lat[f * CHANNEL + lane]);
                float m = fmaxf(fmaxf(s[0], s[1]), fmaxf(s[2], s[3]));
                float d = 0.f;
                #pragma unroll
                for (int f = 0; f < N_FACTORS; ++f) { s[f] = expf(s[f] - m); d += s[f]; }
                float gate = 0.f;
                #pragma unroll
                for (int f = 0; f < N_FACTORS; ++f)
                    gate += s_dis[f * CHANNEL + lane] * (s[f] / d);
                __builtin_nontemporal_store(acc * gate + acc,
                                            &user_agg[(size_t)gu * CHANNEL + lane]);
            }
            #undef ULD
        }
    }
}

extern "C" void kernel_launch(void* const* d_in, const int* in_sizes, int n_in,
                              void* d_out, int out_size, void* d_ws, size_t ws_size,
                              hipStream_t stream) {
    const float* entity_emb    = (const float*)d_in[0];
    const float* user_emb      = (const float*)d_in[1];
    const float* latent_emb    = (const float*)d_in[2];
    const float* weight        = (const float*)d_in[3];
    const float* dwa           = (const float*)d_in[4];
    const float* interact_vals = (const float*)d_in[5];
    const int*   head          = (const int*)d_in[6];
    const int*   tail          = (const int*)d_in[7];
    const int*   edge_type     = (const int*)d_in[8];
    const int*   irows         = (const int*)d_in[9];
    const int*   icols         = (const int*)d_in[10];

    float* entity_agg = (float*)d_out;                                 // [N_ENTITIES,64]
    float* user_agg   = (float*)d_out + (size_t)N_ENTITIES * CHANNEL;  // [N_USERS,64]

    // workspace layout
    int*   wp_e   = (int*)d_ws;                   // NBE
    int*   wp_u   = wp_e + NBE;                   // NBU
    int*   uctr   = wp_u + NBU;                   // 1 (work-steal counter)
    int*   coff_e = uctr + 1;                     // NBE+1
    int*   coff_u = coff_e + NBE + 1;             // NBU+1
    int*   pay_e  = coff_u + NBU + 1;             // N_EDGES
    int*   payA_u = pay_e + N_EDGES;              // N_INTER
    float* payB_u = (float*)(payA_u + N_INTER);   // N_INTER
    float* disen  = payB_u + N_INTER;             // 4*64
    u16*   emb16  = (u16*)(disen + N_FACTORS * CHANNEL);  // N_ENTITIES*64

    size_t need_bf16 = (size_t)((char*)(emb16 + (size_t)N_ENTITIES * CHANNEL) - (char*)d_ws);
    bool use_bf16 = (ws_size >= need_bf16);
    if (!use_bf16) emb16 = (u16*)d_ws;   // unused dummy

    // zero write-pointers + work counter (contiguous)
    hipMemsetAsync(wp_e, 0, (size_t)(NBE + NBU + 1) * sizeof(int), stream);

    if (use_bf16) {
        prep_kernel<<<NCONV + 1 + NHIST, 256, 0, stream>>>(
            entity_emb, emb16, dwa, weight, disen, head, irows, wp_e, wp_u);
    } else {
        disen_kernel<<<1, 256, 0, stream>>>(dwa, weight, disen);
        hist_kernel<<<128, 1024, 0, stream>>>(head, irows, wp_e, wp_u);
    }

    scan_kernel<<<1, 1024, 0, stream>>>(wp_e, coff_e, wp_u, coff_u);

    scatter_kernel<<<NTBE + NTBU, 1024, 0, stream>>>(
        head, tail, edge_type, irows, icols, interact_vals,
        wp_e, pay_e, wp_u, payA_u, payB_u);

    if (use_bf16) {
        gather_kernel<true><<<NWORK, 256, 0, stream>>>(
            entity_emb, emb16, weight, user_emb, latent_emb, disen,
            coff_e, pay_e, coff_u, payA_u, payB_u, uctr, entity_agg, user_agg);
    } else {
        gather_kernel<false><<<NWORK, 256, 0, stream>>>(
            entity_emb, emb16, weight, user_emb, latent_emb, disen,
            coff_e, pay_e, coff_u, payA_u, payB_u, uctr, entity_agg, user_agg);
    }
}

// Round 12
// 220.772 us; speedup vs baseline: 1.0706x; 1.0706x over previous
//
#include <hip/hip_runtime.h>

#define N_ENTITIES 100000
#define N_USERS 50000
#define CHANNEL 64
#define N_RELATIONS 16
#define N_FACTORS 4
#define N_EDGES 1600000
#define N_INTER 1000000
#define TMASK ((1 << 17) - 1)

// buckets of 64 rows (scatter and gather granularity)
#define BSH 6
#define BSZ 64
#define NBE 1563      // ceil(100000/64)
#define NBU 782       // ceil(50000/64)
#define CAP_E 1536
#define CAP_U 1792
#define TILE_E 4096
#define TILE_U 4096
#define NTBE 391      // ceil(N_EDGES/TILE_E)
#define NTBU 245      // ceil(N_INTER/TILE_U)
#define NCONV 6250    // N_ENTITIES*CHANNEL/4 / 256
#define NHIST 256     // hist blocks inside prep kernel

typedef unsigned short u16;

__device__ __forceinline__ float wave_reduce_sum(float p) {
    #pragma unroll
    for (int off = 32; off > 0; off >>= 1) p += __shfl_xor(p, off);
    return p;
}

// block-wide (1024 thr) inclusive scan via per-wave shfl scans; total in wsum[15]
__device__ __forceinline__ int block_scan_incl(int v, int* wsum) {
    int lane = threadIdx.x & 63, wid = threadIdx.x >> 6;
    int x = v;
    #pragma unroll
    for (int off = 1; off < 64; off <<= 1) {
        int y = __shfl_up(x, off);
        if (lane >= off) x += y;
    }
    __syncthreads();
    if (lane == 63) wsum[wid] = x;
    __syncthreads();
    if (wid == 0) {
        int s = (lane < 16) ? wsum[lane] : 0;
        #pragma unroll
        for (int off = 1; off < 16; off <<= 1) {
            int y = __shfl_up(s, off);
            if (lane >= off) s += y;
        }
        if (lane < 16) wsum[lane] = s;
    }
    __syncthreads();
    return x + (wid ? wsum[wid - 1] : 0);
}

__device__ __forceinline__ u16 f32_to_bf16_rne(float x) {
    unsigned u = __float_as_uint(x);
    return (u16)((u + 0x7FFFu + ((u >> 16) & 1u)) >> 16);
}

template <bool BF16>
__device__ __forceinline__ float ldrow(const float* __restrict__ e32,
                                       const u16* __restrict__ e16,
                                       int row, int lane) {
    if (BF16) return __uint_as_float(((unsigned)e16[(size_t)row * CHANNEL + lane]) << 16);
    return e32[(size_t)row * CHANNEL + lane];
}

// ---------------------------------------------------------------------------
// disen = softmax(disen_weight_att, axis=-1) @ weight   [4 x 64]
// ---------------------------------------------------------------------------
__device__ __forceinline__ void disen_body(const float* __restrict__ dwa,
                                           const float* __restrict__ weight,
                                           float* __restrict__ disen) {
    int f = threadIdx.x >> 6;
    int c = threadIdx.x & 63;
    float m = -INFINITY;
    #pragma unroll
    for (int r = 0; r < N_RELATIONS; ++r) m = fmaxf(m, dwa[f * N_RELATIONS + r]);
    float denom = 0.f, acc = 0.f;
    #pragma unroll
    for (int r = 0; r < N_RELATIONS; ++r) {
        float e = expf(dwa[f * N_RELATIONS + r] - m);
        denom += e;
        acc += e * weight[r * CHANNEL + c];
    }
    disen[f * CHANNEL + c] = acc / denom;
}

__global__ void disen_kernel(const float* __restrict__ dwa,
                             const float* __restrict__ weight,
                             float* __restrict__ disen) {
    disen_body(dwa, weight, disen);
}

// ---------------------------------------------------------------------------
// PREP: blocks [0,NCONV) bf16-convert; block NCONV disen; rest histogram.
// ---------------------------------------------------------------------------
__global__ __launch_bounds__(256) void prep_kernel(
    const float* __restrict__ src, u16* __restrict__ dst,
    const float* __restrict__ dwa, const float* __restrict__ weight,
    float* __restrict__ disen,
    const int* __restrict__ head, const int* __restrict__ irows,
    int* __restrict__ wp_e, int* __restrict__ wp_u) {
    __shared__ int lh[NBE + NBU];
    int bid = blockIdx.x;
    int tid = threadIdx.x;
    if (bid < NCONV) {
        int i = bid * 256 + tid;
        float4 v = ((const float4*)src)[i];
        ushort4 o;
        o.x = f32_to_bf16_rne(v.x);
        o.y = f32_to_bf16_rne(v.y);
        o.z = f32_to_bf16_rne(v.z);
        o.w = f32_to_bf16_rne(v.w);
        ((ushort4*)dst)[i] = o;
        return;
    }
    if (bid == NCONV) { disen_body(dwa, weight, disen); return; }
    for (int i = tid; i < NBE + NBU; i += 256) lh[i] = 0;
    __syncthreads();
    const int NTOT = N_EDGES + N_INTER;
    int hb = bid - NCONV - 1;
    for (int i = hb * 256 + tid; i < NTOT; i += NHIST * 256) {
        if (i < N_EDGES) atomicAdd(&lh[head[i] >> BSH], 1);
        else             atomicAdd(&lh[NBE + (irows[i - N_EDGES] >> BSH)], 1);
    }
    __syncthreads();
    for (int i = tid; i < NBE + NBU; i += 256) {
        int c = lh[i];
        if (c) {
            if (i < NBE) atomicAdd(&wp_e[i], c);
            else         atomicAdd(&wp_u[i - NBE], c);
        }
    }
}

// fallback hist without bf16 conversion
__global__ __launch_bounds__(1024) void hist_kernel(
    const int* __restrict__ head, const int* __restrict__ irows,
    int* __restrict__ wp_e, int* __restrict__ wp_u) {
    __shared__ int lh[NBE + NBU];
    int tid = threadIdx.x;
    for (int i = tid; i < NBE + NBU; i += 1024) lh[i] = 0;
    __syncthreads();
    const int NTOT = N_EDGES + N_INTER;
    for (int i = blockIdx.x * 1024 + tid; i < NTOT; i += gridDim.x * 1024) {
        if (i < N_EDGES) atomicAdd(&lh[head[i] >> BSH], 1);
        else             atomicAdd(&lh[NBE + (irows[i - N_EDGES] >> BSH)], 1);
    }
    __syncthreads();
    for (int i = tid; i < NBE + NBU; i += 1024) {
        int c = lh[i];
        if (c) {
            if (i < NBE) atomicAdd(&wp_e[i], c);
            else         atomicAdd(&wp_u[i - NBE], c);
        }
    }
}

// ---------------------------------------------------------------------------
// One-block exclusive scans: edges (1563, two chunks) and users (782).
// ---------------------------------------------------------------------------
__global__ __launch_bounds__(1024) void scan_kernel(
    int* __restrict__ wp_e, int* __restrict__ coff_e,
    int* __restrict__ wp_u, int* __restrict__ coff_u) {
    __shared__ int wsum[16];
    int tid = threadIdx.x;
    int c0 = wp_e[tid];
    int incl0 = block_scan_incl(c0, wsum);
    int tot0 = wsum[15];
    int i1 = 1024 + tid;
    int c1 = (i1 < NBE) ? wp_e[i1] : 0;
    int incl1 = block_scan_incl(c1, wsum) + tot0;
    int cu = (tid < NBU) ? wp_u[tid] : 0;
    int inclu = block_scan_incl(cu, wsum);
    { int ex = incl0 - c0; coff_e[tid] = ex; wp_e[tid] = ex; }
    if (i1 < NBE) { int ex = incl1 - c1; coff_e[i1] = ex; wp_e[i1] = ex; }
    if (tid == 0) coff_e[NBE] = N_EDGES;
    if (tid < NBU) { int ex = inclu - cu; coff_u[tid] = ex; wp_u[tid] = ex; }
    if (tid == 0) coff_u[NBU] = N_INTER;
}

// ---------------------------------------------------------------------------
// MERGED multisplit scatter: blocks [0,NTBE) edge tiles; rest inter tiles.
// Edge payload: (head&63)<<21 | (et-1)<<17 | tail.
// Inter payloads: (row&63)<<17 | col ; val.  Nontemporal payload writes.
// ---------------------------------------------------------------------------
__global__ __launch_bounds__(1024) void scatter_kernel(
    const int* __restrict__ head, const int* __restrict__ tail,
    const int* __restrict__ etype,
    const int* __restrict__ irows, const int* __restrict__ icols,
    const float* __restrict__ vals,
    int* __restrict__ wp_e, int* __restrict__ pay_e,
    int* __restrict__ wp_u, int* __restrict__ payA_u, float* __restrict__ payB_u) {
    __shared__ __align__(16) char smem[58624];
    __shared__ int wsum[16];
    int tid = threadIdx.x;
    int bid = blockIdx.x;

    if (bid < NTBE) {
        int* s_hist  = (int*)smem;            // NBE
        int* s_lofs  = s_hist + NBE;          // NBE
        int* s_gbase = s_lofs + NBE;          // NBE
        int* s_pay   = s_gbase + NBE;         // TILE_E
        int* s_dest  = s_pay + TILE_E;        // TILE_E
        int g0 = bid * TILE_E;
        int tilecnt = min(TILE_E, N_EDGES - g0);
        for (int i = tid; i < NBE; i += 1024) s_hist[i] = 0;
        int cb[4], pp[4], rk[4];
        __syncthreads();
        #pragma unroll
        for (int j = 0; j < 4; ++j) {
            int s = j * 1024 + tid;
            if (s < tilecnt) {
                int i = g0 + s;
                int h = head[i];
                cb[j] = h >> BSH;
                pp[j] = ((h & (BSZ - 1)) << 21) | ((etype[i] - 1) << 17) | tail[i];
            } else cb[j] = -1;
        }
        #pragma unroll
        for (int j = 0; j < 4; ++j)
            if (cb[j] >= 0) rk[j] = atomicAdd(&s_hist[cb[j]], 1);
        __syncthreads();
        int c0 = s_hist[tid];
        int incl0 = block_scan_incl(c0, wsum);
        int tot0 = wsum[15];
        int i1 = 1024 + tid;
        int c1 = (i1 < NBE) ? s_hist[i1] : 0;
        int incl1 = block_scan_incl(c1, wsum) + tot0;
        {
            int ex = incl0 - c0;
            s_lofs[tid] = ex;
            if (c0 > 0) s_gbase[tid] = atomicAdd(&wp_e[tid], c0) - ex;
        }
        if (i1 < NBE) {
            int ex = incl1 - c1;
            s_lofs[i1] = ex;
            if (c1 > 0) s_gbase[i1] = atomicAdd(&wp_e[i1], c1) - ex;
        }
        __syncthreads();
        #pragma unroll
        for (int j = 0; j < 4; ++j) {
            if (cb[j] >= 0) {
                int slot = s_lofs[cb[j]] + rk[j];
                s_pay[slot]  = pp[j];
                s_dest[slot] = s_gbase[cb[j]] + slot;
            }
        }
        __syncthreads();
        #pragma unroll
        for (int j = 0; j < 4; ++j) {
            int s = j * 1024 + tid;
            if (s < tilecnt)
                __builtin_nontemporal_store(s_pay[s], &pay_e[s_dest[s]]);
        }
    } else {
        int*   s_hist  = (int*)smem;           // NBU
        int*   s_lofs  = s_hist + NBU;         // NBU
        int*   s_gbase = s_lofs + NBU;         // NBU
        int*   s_pay   = s_gbase + NBU;        // TILE_U
        float* s_val   = (float*)(s_pay + TILE_U);  // TILE_U
        int*   s_dest  = (int*)(s_val + TILE_U);    // TILE_U
        int g0 = (bid - NTBE) * TILE_U;
        int tilecnt = min(TILE_U, N_INTER - g0);
        for (int i = tid; i < NBU; i += 1024) s_hist[i] = 0;
        int cb[4], pp[4], rk[4];
        float vv[4];
        __syncthreads();
        #pragma unroll
        for (int j = 0; j < 4; ++j) {
            int s = j * 1024 + tid;
            if (s < tilecnt) {
                int i = g0 + s;
                int u = irows[i];
                cb[j] = u >> BSH;
                pp[j] = ((u & (BSZ - 1)) << 17) | icols[i];
                vv[j] = vals[i];
            } else cb[j] = -1;
        }
        #pragma unroll
        for (int j = 0; j < 4; ++j)
            if (cb[j] >= 0) rk[j] = atomicAdd(&s_hist[cb[j]], 1);
        __syncthreads();
        int c0 = (tid < NBU) ? s_hist[tid] : 0;
        int incl0 = block_scan_incl(c0, wsum);
        if (tid < NBU) {
            int ex = incl0 - c0;
            s_lofs[tid] = ex;
            if (c0 > 0) s_gbase[tid] = atomicAdd(&wp_u[tid], c0) - ex;
        }
        __syncthreads();
        #pragma unroll
        for (int j = 0; j < 4; ++j) {
            if (cb[j] >= 0) {
                int slot = s_lofs[cb[j]] + rk[j];
                s_pay[slot]  = pp[j];
                s_val[slot]  = vv[j];
                s_dest[slot] = s_gbase[cb[j]] + slot;
            }
        }
        __syncthreads();
        #pragma unroll
        for (int j = 0; j < 4; ++j) {
            int s = j * 1024 + tid;
            if (s < tilecnt) {
                __builtin_nontemporal_store(s_pay[s], &payA_u[s_dest[s]]);
                __builtin_nontemporal_store(s_val[s], &payB_u[s_dest[s]]);
            }
        }
    }
}

// ---------------------------------------------------------------------------
// FUSED gather (round-8/10 structure): block < NBE -> edge bucket; else user.
// 256 threads (4 waves x 16 rows). In-LDS counting sort by local row, then
// per-row register-accumulate segments. Nontemporal payload loads + output
// stores (keep emb16 rows resident in L2).
// ---------------------------------------------------------------------------
template <bool BF16>
__global__ __launch_bounds__(256, 8) void gather_kernel(
    const float* __restrict__ entity_emb,
    const u16* __restrict__ emb16,
    const float* __restrict__ weight,
    const float* __restrict__ user_emb,
    const float* __restrict__ latent_emb,
    const float* __restrict__ disen,
    const int* __restrict__ coff_e,
    const int* __restrict__ pay_e,
    const int* __restrict__ coff_u,
    const int* __restrict__ payA_u,
    const float* __restrict__ payB_u,
    float* __restrict__ entity_agg,
    float* __restrict__ user_agg) {
    __shared__ __align__(16) char smem[16896];
    int tid = threadIdx.x;
    int wv = tid >> 6, lane = tid & 63;
    int bid = blockIdx.x;

    if (bid < NBE) {
        // ------------------ edge path ------------------
        float* w65    = (float*)smem;              // 1040
        float* s_attv = w65 + 1040;                // 1024
        int*   s_pay  = (int*)(s_attv + 1024);     // 1536
        int*   s_hist = s_pay + CAP_E;             // 64
        int*   s_scan = s_hist + 64;               // 64

        for (int i = tid; i < N_RELATIONS * CHANNEL; i += 256)
            w65[(i >> 6) * 65 + (i & 63)] = weight[i];
        if (tid < BSZ) s_hist[tid] = 0;
        int kbeg = coff_e[bid];
        int n = min(coff_e[bid + 1] - kbeg, CAP_E);
        __syncthreads();

        // stage + rank (nontemporal payload reads — read exactly once)
        int myp[CAP_E / 256], myr[CAP_E / 256];
        #pragma unroll
        for (int j = 0; j < CAP_E / 256; ++j) {
            int s = j * 256 + tid;
            if (s < n) {
                int p = __builtin_nontemporal_load(&pay_e[kbeg + s]);
                myp[j] = p;
                myr[j] = atomicAdd(&s_hist[p >> 21], 1);
            }
        }
        __syncthreads();
        if (wv == 0) {   // single-wave inclusive scan over 64 bins
            int x = s_hist[lane];
            #pragma unroll
            for (int off = 1; off < 64; off <<= 1) {
                int y = __shfl_up(x, off);
                if (lane >= off) x += y;
            }
            s_scan[lane] = x;
        }
        __syncthreads();
        #pragma unroll
        for (int j = 0; j < CAP_E / 256; ++j) {
            int s = j * 256 + tid;
            if (s < n) {
                int key = myp[j] >> 21;
                s_pay[s_scan[key] - s_hist[key] + myr[j]] = myp[j];
            }
        }

        // att table: wave wv computes rows [wv*16, wv*16+16)  (bf16 head rows)
        int r = lane >> 2, q = lane & 3;
        for (int t = 0; t < 16; ++t) {
            int le = wv * 16 + t;
            int ge = bid * BSZ + le;
            if (ge >= N_ENTITIES) break;
            float eh = ldrow<BF16>(entity_emb, emb16, ge, lane);
            float p = 0.f;
            #pragma unroll
            for (int j = 0; j < 16; ++j)
                p += __shfl(eh, q * 16 + j) * w65[r * 65 + q * 16 + j];
            p += __shfl_xor(p, 1);
            p += __shfl_xor(p, 2);
            if (q == 0) s_attv[(le << 4) + r] = 1.f / (1.f + expf(-p));
        }
        __syncthreads();

        #define EBODY(K) { \
            int pp = s_pay[K]; \
            int et = (pp >> 17) & 15; \
            float v = ldrow<BF16>(entity_emb, emb16, pp & TMASK, lane); \
            acc += s_attv[(le << 4) + et] * v * w65[et * 65 + lane]; }
        for (int t = 0; t < 16; ++t) {
            int le = wv * 16 + t;
            int ge = bid * BSZ + le;
            if (ge >= N_ENTITIES) break;
            int cnt = s_hist[le];
            int ke = s_scan[le];
            int k = ke - cnt;
            float acc = 0.f;
            for (; k + 4 <= ke; k += 4) {
                EBODY(k); EBODY(k + 1); EBODY(k + 2); EBODY(k + 3);
            }
            for (; k < ke; ++k) EBODY(k);
            __builtin_nontemporal_store(acc / fmaxf((float)cnt, 1.0f),
                                        &entity_agg[(size_t)ge * CHANNEL + lane]);
        }
        #undef EBODY
    } else {
        // ------------------ user path ------------------
        int*   s_pay  = (int*)smem;                // 1792
        float* s_val  = (float*)(s_pay + CAP_U);   // 1792
        float* s_lat  = s_val + CAP_U;             // 256
        float* s_dis  = s_lat + 256;               // 256
        int*   s_hist = (int*)(s_dis + 256);       // 64
        int*   s_scan = s_hist + 64;               // 64

        if (tid < BSZ) s_hist[tid] = 0;
        if (tid < N_FACTORS * CHANNEL) {
            s_lat[tid] = latent_emb[tid];
            s_dis[tid] = disen[tid];
        }
        int b = bid - NBE;
        int kbeg = coff_u[b];
        int n = min(coff_u[b + 1] - kbeg, CAP_U);
        __syncthreads();

        int myp[CAP_U / 256], myr[CAP_U / 256];
        float myv[CAP_U / 256];
        #pragma unroll
        for (int j = 0; j < CAP_U / 256; ++j) {
            int s = j * 256 + tid;
            if (s < n) {
                int p = __builtin_nontemporal_load(&payA_u[kbeg + s]);
                myp[j] = p;
                myv[j] = __builtin_nontemporal_load(&payB_u[kbeg + s]);
                myr[j] = atomicAdd(&s_hist[p >> 17], 1);
            }
        }
        __syncthreads();
        if (wv == 0) {
            int x = s_hist[lane];
            #pragma unroll
            for (int off = 1; off < 64; off <<= 1) {
                int y = __shfl_up(x, off);
                if (lane >= off) x += y;
            }
            s_scan[lane] = x;
        }
        __syncthreads();
        #pragma unroll
        for (int j = 0; j < CAP_U / 256; ++j) {
            int s = j * 256 + tid;
            if (s < n) {
                int key = myp[j] >> 17;
                int slot = s_scan[key] - s_hist[key] + myr[j];
                s_pay[slot] = myp[j] & TMASK;
                s_val[slot] = myv[j];
            }
        }
        __syncthreads();

        #define UBODY(K) { \
            float v = ldrow<BF16>(entity_emb, emb16, s_pay[K], lane); \
            acc += s_val[K] * v; }
        for (int t = 0; t < 16; ++t) {
            int lu = wv * 16 + t;
            int gu = b * BSZ + lu;
            if (gu >= N_USERS) break;
            int cnt = s_hist[lu];
            int ke = s_scan[lu];
            int k = ke - cnt;
            float acc = 0.f;
            for (; k + 4 <= ke; k += 4) {
                UBODY(k); UBODY(k + 1); UBODY(k + 2); UBODY(k + 3);
            }
            for (; k < ke; ++k) UBODY(k);

            float ue = user_emb[(size_t)gu * CHANNEL + lane];
            float s[N_FACTORS];
            #pragma unroll
            for (int f = 0; f < N_FACTORS; ++f)
                s[f] = wave_reduce_sum(ue * s_lat[f * CHANNEL + lane]);
            float m = fmaxf(fmaxf(s[0], s[1]), fmaxf(s[2], s[3]));
            float d = 0.f;
            #pragma unroll
            for (int f = 0; f < N_FACTORS; ++f) { s[f] = expf(s[f] - m); d += s[f]; }
            float gate = 0.f;
            #pragma unroll
            for (int f = 0; f < N_FACTORS; ++f)
                gate += s_dis[f * CHANNEL + lane] * (s[f] / d);
            __builtin_nontemporal_store(acc * gate + acc,
                                        &user_agg[(size_t)gu * CHANNEL + lane]);
        }
        #undef UBODY
    }
}

extern "C" void kernel_launch(void* const* d_in, const int* in_sizes, int n_in,
                              void* d_out, int out_size, void* d_ws, size_t ws_size,
                              hipStream_t stream) {
    const float* entity_emb    = (const float*)d_in[0];
    const float* user_emb      = (const float*)d_in[1];
    const float* latent_emb    = (const float*)d_in[2];
    const float* weight        = (const float*)d_in[3];
    const float* dwa           = (const float*)d_in[4];
    const float* interact_vals = (const float*)d_in[5];
    const int*   head          = (const int*)d_in[6];
    const int*   tail          = (const int*)d_in[7];
    const int*   edge_type     = (const int*)d_in[8];
    const int*   irows         = (const int*)d_in[9];
    const int*   icols         = (const int*)d_in[10];

    float* entity_agg = (float*)d_out;                                 // [N_ENTITIES,64]
    float* user_agg   = (float*)d_out + (size_t)N_ENTITIES * CHANNEL;  // [N_USERS,64]

    // workspace layout
    int*   wp_e   = (int*)d_ws;                   // NBE
    int*   wp_u   = wp_e + NBE;                   // NBU
    int*   coff_e = wp_u + NBU;                   // NBE+1
    int*   coff_u = coff_e + NBE + 1;             // NBU+1
    int*   pay_e  = coff_u + NBU + 1;             // N_EDGES
    int*   payA_u = pay_e + N_EDGES;              // N_INTER
    float* payB_u = (float*)(payA_u + N_INTER);   // N_INTER
    float* disen  = payB_u + N_INTER;             // 4*64
    u16*   emb16  = (u16*)(disen + N_FACTORS * CHANNEL);  // N_ENTITIES*64

    size_t need_bf16 = (size_t)((char*)(emb16 + (size_t)N_ENTITIES * CHANNEL) - (char*)d_ws);
    bool use_bf16 = (ws_size >= need_bf16);
    if (!use_bf16) emb16 = (u16*)d_ws;   // unused dummy

    hipMemsetAsync(wp_e, 0, (size_t)(NBE + NBU) * sizeof(int), stream);

    if (use_bf16) {
        prep_kernel<<<NCONV + 1 + NHIST, 256, 0, stream>>>(
            entity_emb, emb16, dwa, weight, disen, head, irows, wp_e, wp_u);
    } else {
        disen_kernel<<<1, 256, 0, stream>>>(dwa, weight, disen);
        hist_kernel<<<128, 1024, 0, stream>>>(head, irows, wp_e, wp_u);
    }

    scan_kernel<<<1, 1024, 0, stream>>>(wp_e, coff_e, wp_u, coff_u);

    scatter_kernel<<<NTBE + NTBU, 1024, 0, stream>>>(
        head, tail, edge_type, irows, icols, interact_vals,
        wp_e, pay_e, wp_u, payA_u, payB_u);

    if (use_bf16) {
        gather_kernel<true><<<NBE + NBU, 256, 0, stream>>>(
            entity_emb, emb16, weight, user_emb, latent_emb, disen,
            coff_e, pay_e, coff_u, payA_u, payB_u, entity_agg, user_agg);
    } else {
        gather_kernel<false><<<NBE + NBU, 256, 0, stream>>>(
            entity_emb, emb16, weight, user_emb, latent_emb, disen,
            coff_e, pay_e, coff_u, payA_u, payB_u, entity_agg, user_agg);
    }
}

// Round 13
// 199.897 us; speedup vs baseline: 1.1825x; 1.1044x over previous
//
#include <hip/hip_runtime.h>

#define N_ENTITIES 100000
#define N_USERS 50000
#define CHANNEL 64
#define N_RELATIONS 16
#define N_FACTORS 4
#define N_EDGES 1600000
#define N_INTER 1000000
#define TMASK ((1 << 17) - 1)

// buckets of 64 rows (scatter and gather granularity)
#define BSH 6
#define BSZ 64
#define NBE 1563      // ceil(100000/64)
#define NBU 782       // ceil(50000/64)
#define CAP_E 1536
#define CAP_U 1792
#define TILE_E 4096
#define TILE_U 4096
#define NTBE 391      // ceil(N_EDGES/TILE_E)
#define NTBU 245      // ceil(N_INTER/TILE_U)
#define NCONV 6250    // N_ENTITIES*CHANNEL/4 / 256
#define NHIST 256     // hist blocks inside prep kernel

typedef unsigned short u16;

__device__ __forceinline__ float wave_reduce_sum(float p) {
    #pragma unroll
    for (int off = 32; off > 0; off >>= 1) p += __shfl_xor(p, off);
    return p;
}

// block-wide (1024 thr) inclusive scan via per-wave shfl scans; total in wsum[15]
__device__ __forceinline__ int block_scan_incl(int v, int* wsum) {
    int lane = threadIdx.x & 63, wid = threadIdx.x >> 6;
    int x = v;
    #pragma unroll
    for (int off = 1; off < 64; off <<= 1) {
        int y = __shfl_up(x, off);
        if (lane >= off) x += y;
    }
    __syncthreads();
    if (lane == 63) wsum[wid] = x;
    __syncthreads();
    if (wid == 0) {
        int s = (lane < 16) ? wsum[lane] : 0;
        #pragma unroll
        for (int off = 1; off < 16; off <<= 1) {
            int y = __shfl_up(s, off);
            if (lane >= off) s += y;
        }
        if (lane < 16) wsum[lane] = s;
    }
    __syncthreads();
    return x + (wid ? wsum[wid - 1] : 0);
}

__device__ __forceinline__ u16 f32_to_bf16_rne(float x) {
    unsigned u = __float_as_uint(x);
    return (u16)((u + 0x7FFFu + ((u >> 16) & 1u)) >> 16);
}

template <bool BF16>
__device__ __forceinline__ float ldrow(const float* __restrict__ e32,
                                       const u16* __restrict__ e16,
                                       int row, int lane) {
    if (BF16) return __uint_as_float(((unsigned)e16[(size_t)row * CHANNEL + lane]) << 16);
    return e32[(size_t)row * CHANNEL + lane];
}

// ---------------------------------------------------------------------------
// disen = softmax(disen_weight_att, axis=-1) @ weight   [4 x 64]
// ---------------------------------------------------------------------------
__device__ __forceinline__ void disen_body(const float* __restrict__ dwa,
                                           const float* __restrict__ weight,
                                           float* __restrict__ disen) {
    int f = threadIdx.x >> 6;
    int c = threadIdx.x & 63;
    float m = -INFINITY;
    #pragma unroll
    for (int r = 0; r < N_RELATIONS; ++r) m = fmaxf(m, dwa[f * N_RELATIONS + r]);
    float denom = 0.f, acc = 0.f;
    #pragma unroll
    for (int r = 0; r < N_RELATIONS; ++r) {
        float e = expf(dwa[f * N_RELATIONS + r] - m);
        denom += e;
        acc += e * weight[r * CHANNEL + c];
    }
    disen[f * CHANNEL + c] = acc / denom;
}

__global__ void disen_kernel(const float* __restrict__ dwa,
                             const float* __restrict__ weight,
                             float* __restrict__ disen) {
    disen_body(dwa, weight, disen);
}

// ---------------------------------------------------------------------------
// PREP: blocks [0,NCONV) bf16-convert; block NCONV disen; rest histogram.
// ---------------------------------------------------------------------------
__global__ __launch_bounds__(256) void prep_kernel(
    const float* __restrict__ src, u16* __restrict__ dst,
    const float* __restrict__ dwa, const float* __restrict__ weight,
    float* __restrict__ disen,
    const int* __restrict__ head, const int* __restrict__ irows,
    int* __restrict__ wp_e, int* __restrict__ wp_u) {
    __shared__ int lh[NBE + NBU];
    int bid = blockIdx.x;
    int tid = threadIdx.x;
    if (bid < NCONV) {
        int i = bid * 256 + tid;
        float4 v = ((const float4*)src)[i];
        ushort4 o;
        o.x = f32_to_bf16_rne(v.x);
        o.y = f32_to_bf16_rne(v.y);
        o.z = f32_to_bf16_rne(v.z);
        o.w = f32_to_bf16_rne(v.w);
        ((ushort4*)dst)[i] = o;
        return;
    }
    if (bid == NCONV) { disen_body(dwa, weight, disen); return; }
    for (int i = tid; i < NBE + NBU; i += 256) lh[i] = 0;
    __syncthreads();
    const int NTOT = N_EDGES + N_INTER;
    int hb = bid - NCONV - 1;
    for (int i = hb * 256 + tid; i < NTOT; i += NHIST * 256) {
        if (i < N_EDGES) atomicAdd(&lh[head[i] >> BSH], 1);
        else             atomicAdd(&lh[NBE + (irows[i - N_EDGES] >> BSH)], 1);
    }
    __syncthreads();
    for (int i = tid; i < NBE + NBU; i += 256) {
        int c = lh[i];
        if (c) {
            if (i < NBE) atomicAdd(&wp_e[i], c);
            else         atomicAdd(&wp_u[i - NBE], c);
        }
    }
}

// fallback hist without bf16 conversion
__global__ __launch_bounds__(1024) void hist_kernel(
    const int* __restrict__ head, const int* __restrict__ irows,
    int* __restrict__ wp_e, int* __restrict__ wp_u) {
    __shared__ int lh[NBE + NBU];
    int tid = threadIdx.x;
    for (int i = tid; i < NBE + NBU; i += 1024) lh[i] = 0;
    __syncthreads();
    const int NTOT = N_EDGES + N_INTER;
    for (int i = blockIdx.x * 1024 + tid; i < NTOT; i += gridDim.x * 1024) {
        if (i < N_EDGES) atomicAdd(&lh[head[i] >> BSH], 1);
        else             atomicAdd(&lh[NBE + (irows[i - N_EDGES] >> BSH)], 1);
    }
    __syncthreads();
    for (int i = tid; i < NBE + NBU; i += 1024) {
        int c = lh[i];
        if (c) {
            if (i < NBE) atomicAdd(&wp_e[i], c);
            else         atomicAdd(&wp_u[i - NBE], c);
        }
    }
}

// ---------------------------------------------------------------------------
// One-block exclusive scans: edges (1563, two chunks) and users (782).
// ---------------------------------------------------------------------------
__global__ __launch_bounds__(1024) void scan_kernel(
    int* __restrict__ wp_e, int* __restrict__ coff_e,
    int* __restrict__ wp_u, int* __restrict__ coff_u) {
    __shared__ int wsum[16];
    int tid = threadIdx.x;
    int c0 = wp_e[tid];
    int incl0 = block_scan_incl(c0, wsum);
    int tot0 = wsum[15];
    int i1 = 1024 + tid;
    int c1 = (i1 < NBE) ? wp_e[i1] : 0;
    int incl1 = block_scan_incl(c1, wsum) + tot0;
    int cu = (tid < NBU) ? wp_u[tid] : 0;
    int inclu = block_scan_incl(cu, wsum);
    { int ex = incl0 - c0; coff_e[tid] = ex; wp_e[tid] = ex; }
    if (i1 < NBE) { int ex = incl1 - c1; coff_e[i1] = ex; wp_e[i1] = ex; }
    if (tid == 0) coff_e[NBE] = N_EDGES;
    if (tid < NBU) { int ex = inclu - cu; coff_u[tid] = ex; wp_u[tid] = ex; }
    if (tid == 0) coff_u[NBU] = N_INTER;
}

// ---------------------------------------------------------------------------
// MERGED multisplit scatter: blocks [0,NTBE) edge tiles; rest inter tiles.
// Edge payload: (head&63)<<21 | (et-1)<<17 | tail.
// Inter payloads: (row&63)<<17 | col ; val.
// ---------------------------------------------------------------------------
__global__ __launch_bounds__(1024) void scatter_kernel(
    const int* __restrict__ head, const int* __restrict__ tail,
    const int* __restrict__ etype,
    const int* __restrict__ irows, const int* __restrict__ icols,
    const float* __restrict__ vals,
    int* __restrict__ wp_e, int* __restrict__ pay_e,
    int* __restrict__ wp_u, int* __restrict__ payA_u, float* __restrict__ payB_u) {
    __shared__ __align__(16) char smem[58624];
    __shared__ int wsum[16];
    int tid = threadIdx.x;
    int bid = blockIdx.x;

    if (bid < NTBE) {
        int* s_hist  = (int*)smem;            // NBE
        int* s_lofs  = s_hist + NBE;          // NBE
        int* s_gbase = s_lofs + NBE;          // NBE
        int* s_pay   = s_gbase + NBE;         // TILE_E
        int* s_dest  = s_pay + TILE_E;        // TILE_E
        int g0 = bid * TILE_E;
        int tilecnt = min(TILE_E, N_EDGES - g0);
        for (int i = tid; i < NBE; i += 1024) s_hist[i] = 0;
        int cb[4], pp[4], rk[4];
        __syncthreads();
        #pragma unroll
        for (int j = 0; j < 4; ++j) {
            int s = j * 1024 + tid;
            if (s < tilecnt) {
                int i = g0 + s;
                int h = head[i];
                cb[j] = h >> BSH;
                pp[j] = ((h & (BSZ - 1)) << 21) | ((etype[i] - 1) << 17) | tail[i];
            } else cb[j] = -1;
        }
        #pragma unroll
        for (int j = 0; j < 4; ++j)
            if (cb[j] >= 0) rk[j] = atomicAdd(&s_hist[cb[j]], 1);
        __syncthreads();
        int c0 = s_hist[tid];
        int incl0 = block_scan_incl(c0, wsum);
        int tot0 = wsum[15];
        int i1 = 1024 + tid;
        int c1 = (i1 < NBE) ? s_hist[i1] : 0;
        int incl1 = block_scan_incl(c1, wsum) + tot0;
        {
            int ex = incl0 - c0;
            s_lofs[tid] = ex;
            if (c0 > 0) s_gbase[tid] = atomicAdd(&wp_e[tid], c0) - ex;
        }
        if (i1 < NBE) {
            int ex = incl1 - c1;
            s_lofs[i1] = ex;
            if (c1 > 0) s_gbase[i1] = atomicAdd(&wp_e[i1], c1) - ex;
        }
        __syncthreads();
        #pragma unroll
        for (int j = 0; j < 4; ++j) {
            if (cb[j] >= 0) {
                int slot = s_lofs[cb[j]] + rk[j];
                s_pay[slot]  = pp[j];
                s_dest[slot] = s_gbase[cb[j]] + slot;
            }
        }
        __syncthreads();
        #pragma unroll
        for (int j = 0; j < 4; ++j) {
            int s = j * 1024 + tid;
            if (s < tilecnt) pay_e[s_dest[s]] = s_pay[s];
        }
    } else {
        int*   s_hist  = (int*)smem;           // NBU
        int*   s_lofs  = s_hist + NBU;         // NBU
        int*   s_gbase = s_lofs + NBU;         // NBU
        int*   s_pay   = s_gbase + NBU;        // TILE_U
        float* s_val   = (float*)(s_pay + TILE_U);  // TILE_U
        int*   s_dest  = (int*)(s_val + TILE_U);    // TILE_U
        int g0 = (bid - NTBE) * TILE_U;
        int tilecnt = min(TILE_U, N_INTER - g0);
        for (int i = tid; i < NBU; i += 1024) s_hist[i] = 0;
        int cb[4], pp[4], rk[4];
        float vv[4];
        __syncthreads();
        #pragma unroll
        for (int j = 0; j < 4; ++j) {
            int s = j * 1024 + tid;
            if (s < tilecnt) {
                int i = g0 + s;
                int u = irows[i];
                cb[j] = u >> BSH;
                pp[j] = ((u & (BSZ - 1)) << 17) | icols[i];
                vv[j] = vals[i];
            } else cb[j] = -1;
        }
        #pragma unroll
        for (int j = 0; j < 4; ++j)
            if (cb[j] >= 0) rk[j] = atomicAdd(&s_hist[cb[j]], 1);
        __syncthreads();
        int c0 = (tid < NBU) ? s_hist[tid] : 0;
        int incl0 = block_scan_incl(c0, wsum);
        if (tid < NBU) {
            int ex = incl0 - c0;
            s_lofs[tid] = ex;
            if (c0 > 0) s_gbase[tid] = atomicAdd(&wp_u[tid], c0) - ex;
        }
        __syncthreads();
        #pragma unroll
        for (int j = 0; j < 4; ++j) {
            if (cb[j] >= 0) {
                int slot = s_lofs[cb[j]] + rk[j];
                s_pay[slot]  = pp[j];
                s_val[slot]  = vv[j];
                s_dest[slot] = s_gbase[cb[j]] + slot;
            }
        }
        __syncthreads();
        #pragma unroll
        for (int j = 0; j < 4; ++j) {
            int s = j * 1024 + tid;
            if (s < tilecnt) {
                payA_u[s_dest[s]] = s_pay[s];
                payB_u[s_dest[s]] = s_val[s];
            }
        }
    }
}

// ---------------------------------------------------------------------------
// FUSED gather (round-8 structure): block < NBE -> edge bucket; else user.
// 256 threads (4 waves x 16 rows). In-LDS counting sort by local row, then
// per-row register-accumulate segments. Nontemporal output stores.
// ---------------------------------------------------------------------------
template <bool BF16>
__global__ __launch_bounds__(256, 8) void gather_kernel(
    const float* __restrict__ entity_emb,
    const u16* __restrict__ emb16,
    const float* __restrict__ weight,
    const float* __restrict__ user_emb,
    const float* __restrict__ latent_emb,
    const float* __restrict__ disen,
    const int* __restrict__ coff_e,
    const int* __restrict__ pay_e,
    const int* __restrict__ coff_u,
    const int* __restrict__ payA_u,
    const float* __restrict__ payB_u,
    float* __restrict__ entity_agg,
    float* __restrict__ user_agg) {
    __shared__ __align__(16) char smem[16896];
    int tid = threadIdx.x;
    int wv = tid >> 6, lane = tid & 63;
    int bid = blockIdx.x;

    if (bid < NBE) {
        // ------------------ edge path ------------------
        float* w65    = (float*)smem;              // 1040
        float* s_attv = w65 + 1040;                // 1024
        int*   s_pay  = (int*)(s_attv + 1024);     // 1536
        int*   s_hist = s_pay + CAP_E;             // 64
        int*   s_scan = s_hist + 64;               // 64

        for (int i = tid; i < N_RELATIONS * CHANNEL; i += 256)
            w65[(i >> 6) * 65 + (i & 63)] = weight[i];
        if (tid < BSZ) s_hist[tid] = 0;
        int kbeg = coff_e[bid];
        int n = min(coff_e[bid + 1] - kbeg, CAP_E);
        __syncthreads();

        // stage + rank
        int myp[CAP_E / 256], myr[CAP_E / 256];
        #pragma unroll
        for (int j = 0; j < CAP_E / 256; ++j) {
            int s = j * 256 + tid;
            if (s < n) {
                int p = pay_e[kbeg + s];
                myp[j] = p;
                myr[j] = atomicAdd(&s_hist[p >> 21], 1);
            }
        }
        __syncthreads();
        if (wv == 0) {   // single-wave inclusive scan over 64 bins
            int x = s_hist[lane];
            #pragma unroll
            for (int off = 1; off < 64; off <<= 1) {
                int y = __shfl_up(x, off);
                if (lane >= off) x += y;
            }
            s_scan[lane] = x;
        }
        __syncthreads();
        #pragma unroll
        for (int j = 0; j < CAP_E / 256; ++j) {
            int s = j * 256 + tid;
            if (s < n) {
                int key = myp[j] >> 21;
                s_pay[s_scan[key] - s_hist[key] + myr[j]] = myp[j];
            }
        }

        // att table: wave wv computes rows [wv*16, wv*16+16)  (bf16 head rows)
        int r = lane >> 2, q = lane & 3;
        for (int t = 0; t < 16; ++t) {
            int le = wv * 16 + t;
            int ge = bid * BSZ + le;
            if (ge >= N_ENTITIES) break;
            float eh = ldrow<BF16>(entity_emb, emb16, ge, lane);
            float p = 0.f;
            #pragma unroll
            for (int j = 0; j < 16; ++j)
                p += __shfl(eh, q * 16 + j) * w65[r * 65 + q * 16 + j];
            p += __shfl_xor(p, 1);
            p += __shfl_xor(p, 2);
            if (q == 0) s_attv[(le << 4) + r] = 1.f / (1.f + expf(-p));
        }
        __syncthreads();

        #define EBODY(K) { \
            int pp = s_pay[K]; \
            int et = (pp >> 17) & 15; \
            float v = ldrow<BF16>(entity_emb, emb16, pp & TMASK, lane); \
            acc += s_attv[(le << 4) + et] * v * w65[et * 65 + lane]; }
        for (int t = 0; t < 16; ++t) {
            int le = wv * 16 + t;
            int ge = bid * BSZ + le;
            if (ge >= N_ENTITIES) break;
            int cnt = s_hist[le];
            int ke = s_scan[le];
            int k = ke - cnt;
            float acc = 0.f;
            for (; k + 4 <= ke; k += 4) {
                EBODY(k); EBODY(k + 1); EBODY(k + 2); EBODY(k + 3);
            }
            for (; k < ke; ++k) EBODY(k);
            __builtin_nontemporal_store(acc / fmaxf((float)cnt, 1.0f),
                                        &entity_agg[(size_t)ge * CHANNEL + lane]);
        }
        #undef EBODY
    } else {
        // ------------------ user path ------------------
        int*   s_pay  = (int*)smem;                // 1792
        float* s_val  = (float*)(s_pay + CAP_U);   // 1792
        float* s_lat  = s_val + CAP_U;             // 256
        float* s_dis  = s_lat + 256;               // 256
        int*   s_hist = (int*)(s_dis + 256);       // 64
        int*   s_scan = s_hist + 64;               // 64

        if (tid < BSZ) s_hist[tid] = 0;
        if (tid < N_FACTORS * CHANNEL) {
            s_lat[tid] = latent_emb[tid];
            s_dis[tid] = disen[tid];
        }
        int b = bid - NBE;
        int kbeg = coff_u[b];
        int n = min(coff_u[b + 1] - kbeg, CAP_U);
        __syncthreads();

        int myp[CAP_U / 256], myr[CAP_U / 256];
        float myv[CAP_U / 256];
        #pragma unroll
        for (int j = 0; j < CAP_U / 256; ++j) {
            int s = j * 256 + tid;
            if (s < n) {
                int p = payA_u[kbeg + s];
                myp[j] = p;
                myv[j] = payB_u[kbeg + s];
                myr[j] = atomicAdd(&s_hist[p >> 17], 1);
            }
        }
        __syncthreads();
        if (wv == 0) {
            int x = s_hist[lane];
            #pragma unroll
            for (int off = 1; off < 64; off <<= 1) {
                int y = __shfl_up(x, off);
                if (lane >= off) x += y;
            }
            s_scan[lane] = x;
        }
        __syncthreads();
        #pragma unroll
        for (int j = 0; j < CAP_U / 256; ++j) {
            int s = j * 256 + tid;
            if (s < n) {
                int key = myp[j] >> 17;
                int slot = s_scan[key] - s_hist[key] + myr[j];
                s_pay[slot] = myp[j] & TMASK;
                s_val[slot] = myv[j];
            }
        }
        __syncthreads();

        #define UBODY(K) { \
            float v = ldrow<BF16>(entity_emb, emb16, s_pay[K], lane); \
            acc += s_val[K] * v; }
        for (int t = 0; t < 16; ++t) {
            int lu = wv * 16 + t;
            int gu = b * BSZ + lu;
            if (gu >= N_USERS) break;
            int cnt = s_hist[lu];
            int ke = s_scan[lu];
            int k = ke - cnt;
            float acc = 0.f;
            for (; k + 4 <= ke; k += 4) {
                UBODY(k); UBODY(k + 1); UBODY(k + 2); UBODY(k + 3);
            }
            for (; k < ke; ++k) UBODY(k);

            float ue = user_emb[(size_t)gu * CHANNEL + lane];
            float s[N_FACTORS];
            #pragma unroll
            for (int f = 0; f < N_FACTORS; ++f)
                s[f] = wave_reduce_sum(ue * s_lat[f * CHANNEL + lane]);
            float m = fmaxf(fmaxf(s[0], s[1]), fmaxf(s[2], s[3]));
            float d = 0.f;
            #pragma unroll
            for (int f = 0; f < N_FACTORS; ++f) { s[f] = expf(s[f] - m); d += s[f]; }
            float gate = 0.f;
            #pragma unroll
            for (int f = 0; f < N_FACTORS; ++f)
                gate += s_dis[f * CHANNEL + lane] * (s[f] / d);
            __builtin_nontemporal_store(acc * gate + acc,
                                        &user_agg[(size_t)gu * CHANNEL + lane]);
        }
        #undef UBODY
    }
}

extern "C" void kernel_launch(void* const* d_in, const int* in_sizes, int n_in,
                              void* d_out, int out_size, void* d_ws, size_t ws_size,
                              hipStream_t stream) {
    const float* entity_emb    = (const float*)d_in[0];
    const float* user_emb      = (const float*)d_in[1];
    const float* latent_emb    = (const float*)d_in[2];
    const float* weight        = (const float*)d_in[3];
    const float* dwa           = (const float*)d_in[4];
    const float* interact_vals = (const float*)d_in[5];
    const int*   head          = (const int*)d_in[6];
    const int*   tail          = (const int*)d_in[7];
    const int*   edge_type     = (const int*)d_in[8];
    const int*   irows         = (const int*)d_in[9];
    const int*   icols         = (const int*)d_in[10];

    float* entity_agg = (float*)d_out;                                 // [N_ENTITIES,64]
    float* user_agg   = (float*)d_out + (size_t)N_ENTITIES * CHANNEL;  // [N_USERS,64]

    // workspace layout
    int*   wp_e   = (int*)d_ws;                   // NBE
    int*   wp_u   = wp_e + NBE;                   // NBU
    int*   coff_e = wp_u + NBU;                   // NBE+1
    int*   coff_u = coff_e + NBE + 1;             // NBU+1
    int*   pay_e  = coff_u + NBU + 1;             // N_EDGES
    int*   payA_u = pay_e + N_EDGES;              // N_INTER
    float* payB_u = (float*)(payA_u + N_INTER);   // N_INTER
    float* disen  = payB_u + N_INTER;             // 4*64
    u16*   emb16  = (u16*)(disen + N_FACTORS * CHANNEL);  // N_ENTITIES*64

    size_t need_bf16 = (size_t)((char*)(emb16 + (size_t)N_ENTITIES * CHANNEL) - (char*)d_ws);
    bool use_bf16 = (ws_size >= need_bf16);
    if (!use_bf16) emb16 = (u16*)d_ws;   // unused dummy

    hipMemsetAsync(wp_e, 0, (size_t)(NBE + NBU) * sizeof(int), stream);

    if (use_bf16) {
        prep_kernel<<<NCONV + 1 + NHIST, 256, 0, stream>>>(
            entity_emb, emb16, dwa, weight, disen, head, irows, wp_e, wp_u);
    } else {
        disen_kernel<<<1, 256, 0, stream>>>(dwa, weight, disen);
        hist_kernel<<<128, 1024, 0, stream>>>(head, irows, wp_e, wp_u);
    }

    scan_kernel<<<1, 1024, 0, stream>>>(wp_e, coff_e, wp_u, coff_u);

    scatter_kernel<<<NTBE + NTBU, 1024, 0, stream>>>(
        head, tail, edge_type, irows, icols, interact_vals,
        wp_e, pay_e, wp_u, payA_u, payB_u);

    if (use_bf16) {
        gather_kernel<true><<<NBE + NBU, 256, 0, stream>>>(
            entity_emb, emb16, weight, user_emb, latent_emb, disen,
            coff_e, pay_e, coff_u, payA_u, payB_u, entity_agg, user_agg);
    } else {
        gather_kernel<false><<<NBE + NBU, 256, 0, stream>>>(
            entity_emb, emb16, weight, user_emb, latent_emb, disen,
            coff_e, pay_e, coff_u, payA_u, payB_u, entity_agg, user_agg);
    }
}